// Round 1
// 202.083 us; speedup vs baseline: 1.0277x; 1.0277x over previous
//
#include <hip/hip_runtime.h>
#include <cstdint>

// CTC loss, tf.nn.ctc_loss semantics (blank_index=0), B=1024 T=256 C=128 L=32.
// One block (512 thr = 8 waves) per batch element.
//
// Round-9: kill the per-chunk vmcnt(0) drain. __syncthreads() emits
// `s_waitcnt vmcnt(0)` before s_barrier, so R8 serialized on the FULL
// transfer of chunk c+1 every iteration (~2x HBM floor). raw[] staging is
// wave-private (wave w stages and reads exactly rows 2w/2w+1), so the only
// cross-wave dependency is Gc publication. Therefore:
//   - barrier = {s_waitcnt lgkmcnt(0); s_barrier}  (prefetch stays in flight)
//   - raw consumption gated by per-wave counted `s_waitcnt vmcnt(1)`
//     (each wave issues exactly 1 global_load_lds per chunk)
//   - wave-0 DP(c-1) moved BEFORE the vmcnt wait so the serial alpha
//     recurrence overlaps chunk-c's HBM transfer
//   - softmax kept in exp2/log2 domain end-to-end (reuse x*LOG2E, fold LN2
//     once in the epilogue)
// LDS 34.5 KB unchanged -> 4 blocks/CU, whole grid resident in one round.
// Predicted: per-chunk time -> max(32KB/CU HBM time ~1.35us, compute);
// kernel ~= HBM floor (~22-27 us vs ~51 us before).

#define CTC_BLANK 0
#define CTC_PAD   127
#define NEG       (-1e30f)
#define LOG2E     1.44269504088896340736f
#define LN2       0.69314718055994530942f

constexpr int Bn = 1024, Tn = 256, Cn = 128, Ln = 32;
constexpr int NSLOT = Ln + 1;     // 33: blank + up to 32 distinct labels
constexpr int CR  = 16;           // rows per chunk
constexpr int NCH = Tn / CR;      // 16 chunks
constexpr int CF  = CR * Cn;      // 2048 floats per chunk (8 KB)

__device__ __forceinline__ float fexp2(float x) { return __builtin_amdgcn_exp2f(x); }
__device__ __forceinline__ float flog2(float x) { return __builtin_amdgcn_logf(x); }

// s += dpp_shift(s); invalid source lanes contribute 0 (bound_ctrl:0).
template <int CTRL>
__device__ __forceinline__ float dpp_add(float s) {
    int v = __builtin_amdgcn_update_dpp(0, __float_as_int(s), CTRL, 0xF, 0xF, true);
    return s + __int_as_float(v);
}
// lane i <- src[lane i-1]; lane 0 <- old.  (wave_shr:1, VALU pipe)
__device__ __forceinline__ float dpp_wave_shr1(float src, float old) {
    return __int_as_float(__builtin_amdgcn_update_dpp(
        __float_as_int(old), __float_as_int(src), 0x138, 0xF, 0xF, false));
}
// async global->LDS, 16 B/lane; lptr must be wave-uniform (lane lands at
// lptr + lane*16).
__device__ __forceinline__ void gl_lds16(const float* g, float* l) {
    __builtin_amdgcn_global_load_lds(
        (const __attribute__((address_space(1))) uint32_t*)g,
        (__attribute__((address_space(3))) uint32_t*)l, 16, 0, 0);
}

__global__ __launch_bounds__(512, 8) void ctc_fused_kernel(
        const int*   __restrict__ y_true,   // [B, L]
        const float* __restrict__ y_pred,   // [B, T, C]
        float*       __restrict__ out)      // [B]
{
    __shared__ __align__(16) float raw[2][CF];     // 16 KB raw logit chunks
    __shared__ _Float16 Gc[Tn * NSLOT];            // 16.9 KB, log2-domain
    __shared__ int   labels[Ln];
    __shared__ __align__(16) int cmap[Cn];
    __shared__ int   used[Cn];
    __shared__ int   wcnt[8];
    __shared__ float partS[16];

    const int b    = blockIdx.x;
    const int tid  = threadIdx.x;
    const int lane = tid & 63;
    const int wave = tid >> 6;

    const float* gbase = y_pred + (size_t)b * Tn * Cn;

    // issue chunk c into raw[buf]: one global_load_lds per wave (wave-private)
    auto stage = [&](int c, int buf) {
        gl_lds16(gbase + c * CF + tid * 4, &raw[buf][wave * 256]);
    };

    stage(0, 0);   // chunk-0 latency hides behind the cmap build below

    // ---- class->slot map ----
    if (tid < Ln) labels[tid] = y_true[b * Ln + tid];
    if (tid < Cn) used[tid] = 0;
    __syncthreads();
    if (tid == 0) used[CTC_BLANK] = 1;
    if (tid < Ln) used[labels[tid]] = 1;   // racy same-value writes: fine
    __syncthreads();
    {
        bool f = (tid < Cn) && (used[tid] != 0);
        unsigned long long m = __ballot(f);
        if (lane == 0) wcnt[wave] = __popcll(m);
        __syncthreads();
        int base = 0;
        for (int w = 0; w < wave; ++w) base += wcnt[w];
        if (tid < Cn)
            cmap[tid] = f ? (base + __popcll(m & ((1ull << lane) - 1ull))) : -1;
        __syncthreads();   // also drains chunk-0 global_load_lds (vmcnt=0 here)
    }

    // ---- per-thread processing constants ----
    const int half = lane >> 5;
    const int l32  = lane & 31;
    const int4 cm  = ((const int4*)cmap)[l32];
    float acc = 0.f;   // log2-domain partial lse sum

    // ---- DP constants (uniform across waves; only wave 0 runs DP) ----
    const int  i      = lane;                 // lane i: states 2i, 2i+1
    const bool validO = (i < Ln);
    const bool validE = (i <= Ln);
    const int  myLab   = validO ? labels[i] : -1;
    const int  prevLab = (i >= 1 && i < Ln) ? labels[i - 1] : -1;
    const int  slotO   = validO ? cmap[myLab] : 0;
    const bool skipO   = (i >= 1 && i < Ln) &&
                         (myLab != CTC_BLANK) && (myLab != prevLab);
    const int  len = __popcll(__ballot(validO && (myLab != CTC_PAD)));
    float aE = NEG, aO = NEG;

    auto dp_chunk = [&](int t0, int t1) {
        int t = t0;
        if (t == 0) {
            aE = (i == 0) ? (float)Gc[0]     : NEG;
            aO = (i == 0) ? (float)Gc[slotO] : NEG;
            t = 1;
        }
        float pB[2], pO[2];
        const int ta = t, tb = (t + 1 < t1) ? t + 1 : t1 - 1;
        pB[0] = (float)Gc[ta * NSLOT]; pO[0] = (float)Gc[ta * NSLOT + slotO];
        pB[1] = (float)Gc[tb * NSLOT]; pO[1] = (float)Gc[tb * NSLOT + slotO];
        int k = 0;
        #pragma unroll 2
        for (; t < t1; ++t) {
            const float lpB = pB[k], lpO = pO[k];
            const int tp = (t + 2 < t1) ? t + 2 : t1 - 1;
            pB[k] = (float)Gc[tp * NSLOT];
            pO[k] = (float)Gc[tp * NSLOT + slotO];
            k ^= 1;

            const float aOup = dpp_wave_shr1(aO, NEG);   // alpha[2i-1]
            const float m  = fmaxf(aE, aOup);
            const float e1 = fexp2(aE - m);
            const float e2 = fexp2(aOup - m);
            const float sE = e1 + e2;
            const float nE = lpB + m + flog2(sE);                // s = 2i
            const float m3 = fmaxf(aO, m);
            const float nO = lpO + m3 +                          // s = 2i+1
                flog2(fexp2(aO - m3) + (skipO ? sE : e1) * fexp2(m - m3));
            aE = validE ? nE : NEG;
            aO = validO ? nO : NEG;
        }
    };

    // ---- pipelined: stage c+1 || DP c-1 || wait c || process c ----
    for (int c = 0; c < NCH; ++c) {
        if (c + 1 < NCH) stage(c + 1, (c + 1) & 1);

        // serial alpha recurrence overlaps chunk-c's transfer (wave 0 only)
        if (wave == 0 && c > 0) dp_chunk((c - 1) * CR, c * CR);

        // counted wait: chunk c landed; chunk c+1 stays in flight across
        // the barrier below. sched_barrier keeps the stage issue above and
        // the raw[] ds_read below this wait.
        __builtin_amdgcn_sched_barrier(0);
        if (c + 1 < NCH) asm volatile("s_waitcnt vmcnt(1)" ::: "memory");
        else             asm volatile("s_waitcnt vmcnt(0)" ::: "memory");
        __builtin_amdgcn_sched_barrier(0);

        // process chunk c: wave w handles rows 2w (lanes 0-31) / 2w+1 (32-63)
        {
            const int rl = 2 * wave + half;        // 0..15 within chunk
            const int r  = c * CR + rl;
            const float4 x = ((const float4*)&raw[c & 1][rl * Cn])[l32];
            const float e0 = x.x * LOG2E, e1 = x.y * LOG2E,
                        e2 = x.z * LOG2E, e3 = x.w * LOG2E;
            if (cm.x >= 0) Gc[r * NSLOT + cm.x] = (_Float16)e0;
            if (cm.y >= 0) Gc[r * NSLOT + cm.y] = (_Float16)e1;
            if (cm.z >= 0) Gc[r * NSLOT + cm.z] = (_Float16)e2;
            if (cm.w >= 0) Gc[r * NSLOT + cm.w] = (_Float16)e3;
            float s = fexp2(e0) + fexp2(e1) + fexp2(e2) + fexp2(e3);
            s = dpp_add<0x111>(s);   // row_shr:1
            s = dpp_add<0x112>(s);   // row_shr:2
            s = dpp_add<0x114>(s);   // row_shr:4
            s = dpp_add<0x118>(s);   // row_shr:8
            s = dpp_add<0x142>(s);   // row_bcast:15
            acc += flog2(s);         // valid on lanes 31 / 63 (log2 domain)
        }
        if (c == NCH - 1 && l32 == 31) partS[wave * 2 + half] = acc;

        // publish Gc (and partS) WITHOUT draining the vmcnt prefetch queue
        asm volatile("s_waitcnt lgkmcnt(0)" ::: "memory");
        __builtin_amdgcn_s_barrier();
    }

    // ---- final DP chunk + epilogue ----
    if (wave == 0) {
        dp_chunk(Tn - CR, Tn);
        const float v1 = __shfl(aE, len, 64);       // alpha[2*len]
        const float v2 = __shfl(aO, len - 1, 64);   // alpha[2*len-1]
        if (i == 0) {
            float S = 0.f;
            #pragma unroll
            for (int j = 0; j < 16; ++j) S += partS[j];
            const float mm = fmaxf(v1, v2);
            const float L2 = mm + flog2(fexp2(v1 - mm) + fexp2(v2 - mm));
            out[b] = LN2 * (S - L2);   // both terms log2-domain
        }
    }
}

extern "C" void kernel_launch(void* const* d_in, const int* in_sizes, int n_in,
                              void* d_out, int out_size, void* d_ws, size_t ws_size,
                              hipStream_t stream) {
    const int*   y_true = (const int*)d_in[0];
    const float* y_pred = (const float*)d_in[1];
    float*       out    = (float*)d_out;
    ctc_fused_kernel<<<Bn, 512, 0, stream>>>(y_true, y_pred, out);
}